// Round 5
// baseline (2608.526 us; speedup 1.0000x reference)
//
#include <hip/hip_runtime.h>
#include <hip/hip_cooperative_groups.h>
#include <math.h>

// Decoder_910533066914 — R5: persistent cooperative recurrence (Wh in VGPRs,
// c in registers, grid.sync per step) + coalesced LDS-staged logits epilogue.
// Math identical to R4 (passed, absmax 9.8e-4).

namespace cg = cooperative_groups;

typedef __bf16 bf16;
typedef _Float16 fp16;
typedef __attribute__((ext_vector_type(8))) __bf16 bf16x8;
typedef __attribute__((ext_vector_type(4))) float f32x4;

constexpr int B = 32, T = 64, S = 64, D = 1024, A = 512, E = 256, L = 1024, V = 12000;
constexpr int G = 4096;
constexpr size_t N_PROBS = (size_t)B * T * V;

__device__ inline void load_lds16(const void* g, void* l) {
  __builtin_amdgcn_global_load_lds(
      (const __attribute__((address_space(1))) unsigned int*)g,
      (__attribute__((address_space(3))) unsigned int*)l, 16, 0, 0);
}

// ---------------- attention precompute ----------------

__global__ void k_v2(const float* __restrict__ W2, const float* __restrict__ Va,
                     float* __restrict__ v2) {
  int gw = (blockIdx.x * blockDim.x + threadIdx.x) >> 6;
  int lane = threadIdx.x & 63;
  if (gw >= D) return;
  float acc = 0.f;
  for (int a = lane; a < A; a += 64) acc += W2[(size_t)gw * A + a] * Va[a];
  #pragma unroll
  for (int off = 32; off; off >>= 1) acc += __shfl_down(acc, off);
  if (lane == 0) v2[gw] = acc;
}

__global__ void k_score(const float* __restrict__ options, const float* __restrict__ v2,
                        float* __restrict__ w) {
  int row = (blockIdx.x * blockDim.x + threadIdx.x) >> 6;
  int lane = threadIdx.x & 63;
  if (row >= B * S) return;
  const float* orow = options + (size_t)row * D;
  float acc = 0.f;
  for (int d = lane; d < D; d += 64) acc += orow[d] * v2[d];
  #pragma unroll
  for (int off = 32; off; off >>= 1) acc += __shfl_down(acc, off);
  if (lane == 0) w[row] = acc;
}

// fused: softmax over s + attention output + context  (one block per b)
__global__ __launch_bounds__(256) void k_attnctx(
    const float* __restrict__ options, const float* __restrict__ wat,
    float* __restrict__ oattn, float* __restrict__ ctx) {
  __shared__ float sw[64];
  const int b = blockIdx.x, tid = threadIdx.x;
  if (tid < 64) {
    float v = wat[b * 64 + tid];
    float m = v;
    #pragma unroll
    for (int off = 32; off; off >>= 1) m = fmaxf(m, __shfl_xor(m, off));
    float e = expf(v - m);
    float s = e;
    #pragma unroll
    for (int off = 32; off; off >>= 1) s += __shfl_xor(s, off);
    float res = e / s;
    sw[tid] = res;
    oattn[b * 64 + tid] = res;
  }
  __syncthreads();
  for (int d = tid; d < D; d += 256) {
    float acc = 0.f;
    #pragma unroll 8
    for (int s = 0; s < 64; ++s)
      acc += sw[s] * options[((size_t)(b * 64 + s)) * D + d];
    ctx[b * D + d] = acc;
  }
}

// ---------------- cx = bl + ctx@Wx1, split-K ----------------
__global__ __launch_bounds__(256) void k_cx_part(
    const float* __restrict__ ctx, const float* __restrict__ Wx,
    float* __restrict__ cxp) {
  const int jt = blockIdx.x & 15;
  const int bg = (blockIdx.x >> 4) & 3;
  const int kc = blockIdx.x >> 6;
  const int j = jt * 256 + threadIdx.x;
  const int b0 = bg * 8, d0 = kc * 128;
  float acc[8];
  #pragma unroll
  for (int bb = 0; bb < 8; ++bb) acc[bb] = 0.f;
  for (int d = 0; d < 128; ++d) {
    float wv = Wx[(size_t)(d0 + d) * G + j];
    #pragma unroll
    for (int bb = 0; bb < 8; ++bb)
      acc[bb] = fmaf(ctx[(b0 + bb) * D + d0 + d], wv, acc[bb]);
  }
  #pragma unroll
  for (int bb = 0; bb < 8; ++bb)
    cxp[((size_t)kc * 32 + b0 + bb) * G + j] = acc[bb];
}

__global__ void k_cx_reduce(const float* __restrict__ cxp, const float* __restrict__ bl,
                            float* __restrict__ cx) {
  int i = blockIdx.x * 256 + threadIdx.x;
  float s = bl[i & 4095];
  #pragma unroll
  for (int kc = 0; kc < 8; ++kc) s += cxp[(size_t)kc * 131072 + i];
  cx[i] = s;
}

// ---------------- gathers / transposes (hi/lo split) ----------------

__global__ void k_eg(const int* __restrict__ targets, const float* __restrict__ emb,
                     bf16* __restrict__ eg_hi, bf16* __restrict__ eg_lo) {
  int r = blockIdx.x, e = threadIdx.x;
  int tok = targets[r];
  float x = emb[(size_t)tok * E + e];
  bf16 hi = (bf16)x;
  eg_hi[(size_t)r * E + e] = hi;
  eg_lo[(size_t)r * E + e] = (bf16)(x - (float)hi);
}

__global__ __launch_bounds__(256) void k_wx2t(const float* __restrict__ Wx,
                                              bf16* __restrict__ t_hi,
                                              bf16* __restrict__ t_lo) {
  __shared__ float s[64][65];
  const int et = blockIdx.x >> 6, jt = blockIdx.x & 63;
  const int e0 = et * 64, j0 = jt * 64;
  const int tid = threadIdx.x;
  const int jj = tid & 63;
  #pragma unroll
  for (int k = 0; k < 16; ++k) {
    int ee = k * 4 + (tid >> 6);
    s[ee][jj] = Wx[(size_t)(D + e0 + ee) * G + j0 + jj];
  }
  __syncthreads();
  const int jc = tid >> 2, eq = tid & 3;
  bf16x8 h0, h1, l0, l1;
  #pragma unroll
  for (int i = 0; i < 8; ++i) {
    float a = s[eq * 16 + i][jc], b = s[eq * 16 + 8 + i][jc];
    bf16 ah = (bf16)a, bh = (bf16)b;
    h0[i] = ah; l0[i] = (bf16)(a - (float)ah);
    h1[i] = bh; l1[i] = (bf16)(b - (float)bh);
  }
  size_t dst = (size_t)(j0 + jc) * E + e0 + eq * 16;
  *(bf16x8*)(t_hi + dst) = h0; *(bf16x8*)(t_hi + dst + 8) = h1;
  *(bf16x8*)(t_lo + dst) = l0; *(bf16x8*)(t_lo + dst + 8) = l1;
}

// Whp[rowp][l] = Wh[l][col], rowp = (jj>>2)*16 + g*4 + (jj&3), col = g*1024+jj.
__global__ __launch_bounds__(256) void k_whp(const float* __restrict__ Wh,
                                             bf16* __restrict__ p_hi,
                                             bf16* __restrict__ p_lo) {
  __shared__ float s[64][65];
  const int lt = blockIdx.x & 15, ct = blockIdx.x >> 4;
  const int l0 = lt * 64, c0 = ct * 64;
  const int tid = threadIdx.x;
  const int cc = tid & 63;
  #pragma unroll
  for (int k = 0; k < 16; ++k) {
    int ll = k * 4 + (tid >> 6);
    s[ll][cc] = Wh[(size_t)(l0 + ll) * G + c0 + cc];
  }
  __syncthreads();
  const int c = tid >> 2, lq = tid & 3;
  const int col = c0 + c, g = col >> 10, jj = col & 1023;
  const int rowp = ((jj >> 2) << 4) + (g << 2) + (jj & 3);
  bf16x8 h0, h1, l0v, l1v;
  #pragma unroll
  for (int i = 0; i < 8; ++i) {
    float a = s[lq * 16 + i][c], b = s[lq * 16 + 8 + i][c];
    bf16 ah = (bf16)a, bh = (bf16)b;
    h0[i] = ah; l0v[i] = (bf16)(a - (float)ah);
    h1[i] = bh; l1v[i] = (bf16)(b - (float)bh);
  }
  size_t dst = (size_t)rowp * L + l0 + lq * 16;
  *(bf16x8*)(p_hi + dst) = h0; *(bf16x8*)(p_hi + dst + 8) = h1;
  *(bf16x8*)(p_lo + dst) = l0v; *(bf16x8*)(p_lo + dst + 8) = l1v;
}

__global__ void k_h0split(const float* __restrict__ h0,
                          bf16* __restrict__ h_hi, bf16* __restrict__ h_lo,
                          float* __restrict__ hf32) {
  int i = blockIdx.x * 256 + threadIdx.x;
  float x = h0[i];
  bf16 hi = (bf16)x;
  h_hi[i] = hi;
  h_lo[i] = (bf16)(x - (float)hi);
  hf32[i] = x;
}

// ---------------- pre = Eg@Wx2t^T + cx -> fp16 [2048][4096] ----------------
__global__ __launch_bounds__(256) void k_pre_mfma(
    const bf16* __restrict__ Ah, const bf16* __restrict__ Al,
    const bf16* __restrict__ Bh, const bf16* __restrict__ Bl,
    const float* __restrict__ cx, fp16* __restrict__ pre16) {
  __shared__ __align__(16) char lds[65536];
  char* sAh = lds;
  char* sAl = lds + 16384;
  char* sBh = lds + 32768;
  char* sBl = lds + 49152;
  const int bid = blockIdx.x;
  const int swz = (bid & 7) * 64 + (bid >> 3);
  const int mt = swz >> 5, nt = swz & 31;
  const int m0 = mt * 128, n0 = nt * 128;
  const int tid = threadIdx.x, w = tid >> 6, lane = tid & 63;
  const int wr = w >> 1, wc = w & 1;

  f32x4 acc[4][4];
  #pragma unroll
  for (int i = 0; i < 4; ++i)
    #pragma unroll
    for (int j = 0; j < 4; ++j) acc[i][j] = (f32x4){0.f, 0.f, 0.f, 0.f};

  int rowc[4], sloc[4];
  #pragma unroll
  for (int i = 0; i < 4; ++i) {
    int c = i * 4 + w;
    rowc[i] = c * 8 + (lane >> 3);
    sloc[i] = (lane & 7) ^ (rowc[i] & 7);
  }

  for (int kk = 0; kk < 4; ++kk) {
    if (kk) __syncthreads();
    const char* gah = (const char*)Ah + kk * 128;
    const char* gal = (const char*)Al + kk * 128;
    const char* gbh = (const char*)Bh + kk * 128;
    const char* gbl = (const char*)Bl + kk * 128;
    #pragma unroll
    for (int i = 0; i < 4; ++i) {
      int c = i * 4 + w;
      load_lds16(gah + (size_t)(m0 + rowc[i]) * 512 + sloc[i] * 16, sAh + c * 1024);
      load_lds16(gal + (size_t)(m0 + rowc[i]) * 512 + sloc[i] * 16, sAl + c * 1024);
      load_lds16(gbh + (size_t)(n0 + rowc[i]) * 512 + sloc[i] * 16, sBh + c * 1024);
      load_lds16(gbl + (size_t)(n0 + rowc[i]) * 512 + sloc[i] * 16, sBl + c * 1024);
    }
    __syncthreads();
    #pragma unroll
    for (int ks = 0; ks < 2; ++ks) {
      bf16x8 avh[4], avl[4], bvh[4], bvl[4];
      #pragma unroll
      for (int f = 0; f < 4; ++f) {
        int ra = wr * 64 + f * 16 + (lane & 15);
        int ca = (ks * 4 + (lane >> 4)) ^ (ra & 7);
        avh[f] = *(const bf16x8*)(sAh + ra * 128 + ca * 16);
        avl[f] = *(const bf16x8*)(sAl + ra * 128 + ca * 16);
        int rb = wc * 64 + f * 16 + (lane & 15);
        int cb = (ks * 4 + (lane >> 4)) ^ (rb & 7);
        bvh[f] = *(const bf16x8*)(sBh + rb * 128 + cb * 16);
        bvl[f] = *(const bf16x8*)(sBl + rb * 128 + cb * 16);
      }
      #pragma unroll
      for (int fm = 0; fm < 4; ++fm)
        #pragma unroll
        for (int fn = 0; fn < 4; ++fn) {
          acc[fm][fn] = __builtin_amdgcn_mfma_f32_16x16x32_bf16(avh[fm], bvh[fn], acc[fm][fn], 0, 0, 0);
          acc[fm][fn] = __builtin_amdgcn_mfma_f32_16x16x32_bf16(avh[fm], bvl[fn], acc[fm][fn], 0, 0, 0);
          acc[fm][fn] = __builtin_amdgcn_mfma_f32_16x16x32_bf16(avl[fm], bvh[fn], acc[fm][fn], 0, 0, 0);
        }
    }
  }

  const int r0o = m0 + wr * 64 + ((lane >> 4) << 2);
  const int c0o = n0 + wc * 64 + (lane & 15);
  #pragma unroll
  for (int fn = 0; fn < 4; ++fn) {
    int colg = c0o + fn * 16;
    #pragma unroll
    for (int fm = 0; fm < 4; ++fm) {
      #pragma unroll
      for (int r = 0; r < 4; ++r) {
        int row = r0o + fm * 16 + r;
        float v = acc[fm][fn][r] + cx[(size_t)(row >> 6) * G + colg];
        pre16[(size_t)row * G + colg] = (fp16)v;
      }
    }
  }
}

// ---------------- persistent cooperative recurrence ----------------
// 256 blocks x 512 thr; block jb owns units j = jb*4..+3 (16 Whp rows, in regs).
__global__ __launch_bounds__(512, 1) void k_rec(
    const bf16* __restrict__ Whp_hi, const bf16* __restrict__ Whp_lo,
    const fp16* __restrict__ pre16,
    bf16* __restrict__ hA_hi, bf16* __restrict__ hA_lo,
    bf16* __restrict__ hB_hi, bf16* __restrict__ hB_lo,
    const float* __restrict__ c0, float* __restrict__ cst,
    float* __restrict__ hf32, bf16* __restrict__ Hb16) {
  cg::grid_group grid = cg::this_grid();
  __shared__ float zred[8 * 2 * 64 * 4]; // 16 KB
  __shared__ float zf[32][16];           // 2 KB
  const int jb = blockIdx.x;
  const int tid = threadIdx.x;
  const int w = tid >> 6, lane = tid & 63;
  const int fr = lane & 15, kc = lane >> 4;

  // preload this block's Whp slice into registers (never re-read)
  bf16x8 wbh[4], wbl[4];
  {
    const bf16* ph = Whp_hi + (size_t)(jb * 16 + fr) * L;
    const bf16* pl = Whp_lo + (size_t)(jb * 16 + fr) * L;
    #pragma unroll
    for (int kk = 0; kk < 4; ++kk) {
      const int k0 = (w * 4 + kk) * 32 + kc * 8;
      wbh[kk] = *(const bf16x8*)(ph + k0);
      wbl[kk] = *(const bf16x8*)(pl + k0);
    }
  }
  // c-state in registers (tid<128 owns one (b, j) cell)
  const int gb = tid >> 2, gjo = tid & 3, gj = jb * 4 + gjo;
  float cstate = 0.f;
  if (tid < 128) cstate = c0[gb * 1024 + gj];

  for (int t = 0; t < T; ++t) {
    const bf16* hih = (t & 1) ? hB_hi : hA_hi;
    const bf16* hil = (t & 1) ? hB_lo : hA_lo;
    bf16* hoh = (t & 1) ? hA_hi : hB_hi;
    bf16* hol = (t & 1) ? hA_lo : hB_lo;

    float pf[4];
    if (tid < 128) {
      const size_t pbase = (size_t)(gb * 64 + t) * G + gj;
      #pragma unroll
      for (int g = 0; g < 4; ++g) pf[g] = (float)pre16[pbase + g * 1024];
    }

    f32x4 acc[2];
    acc[0] = (f32x4){0.f, 0.f, 0.f, 0.f};
    acc[1] = (f32x4){0.f, 0.f, 0.f, 0.f};
    #pragma unroll
    for (int kk = 0; kk < 4; ++kk) {
      const int k0 = (w * 4 + kk) * 32 + kc * 8;
      #pragma unroll
      for (int m = 0; m < 2; ++m) {
        const size_t ao = (size_t)(m * 16 + fr) * L + k0;
        bf16x8 ah = *(const bf16x8*)(hih + ao);
        bf16x8 al = *(const bf16x8*)(hil + ao);
        acc[m] = __builtin_amdgcn_mfma_f32_16x16x32_bf16(ah, wbh[kk], acc[m], 0, 0, 0);
        acc[m] = __builtin_amdgcn_mfma_f32_16x16x32_bf16(ah, wbl[kk], acc[m], 0, 0, 0);
        acc[m] = __builtin_amdgcn_mfma_f32_16x16x32_bf16(al, wbh[kk], acc[m], 0, 0, 0);
      }
    }
    #pragma unroll
    for (int m = 0; m < 2; ++m)
      *(f32x4*)&zred[((w * 2 + m) * 64 + lane) * 4] = acc[m];
    __syncthreads();
    {
      const int b = tid >> 4, c = tid & 15;
      const int lane2 = (((b & 15) >> 2) << 4) | c;
      const int reg = b & 3, m = b >> 4;
      float s = 0.f;
      #pragma unroll
      for (int ww = 0; ww < 8; ++ww)
        s += zred[((ww * 2 + m) * 64 + lane2) * 4 + reg];
      zf[b][c] = s;
    }
    __syncthreads();
    if (tid < 128) {
      float zi = zf[gb][gjo] + pf[0];
      float zff = zf[gb][4 + gjo] + pf[1];
      float zg = zf[gb][8 + gjo] + pf[2];
      float zo = zf[gb][12 + gjo] + pf[3];
      float si = 1.f / (1.f + expf(-zi));
      float sf = 1.f / (1.f + expf(-zff));
      float tg = tanhf(zg);
      float so = 1.f / (1.f + expf(-zo));
      float cn = sf * cstate + si * tg;
      float hn = so * tanhf(cn);
      cstate = cn;
      const int hi_idx = gb * 1024 + gj;
      bf16 hh = (bf16)hn;
      hoh[hi_idx] = hh;
      hol[hi_idx] = (bf16)(hn - (float)hh);
      Hb16[(size_t)(gb * 64 + t) * L + gj] = hh;
      if (t == T - 1) {
        cst[hi_idx] = cn;
        hf32[hi_idx] = hn;
      }
    }
    grid.sync();
  }
}

// ---------------- Wd -> Wdt bf16 ----------------
__global__ __launch_bounds__(256) void k_wdt(const float* __restrict__ Wd,
                                             bf16* __restrict__ Wdt) {
  __shared__ float s[64][65];
  const int lt = blockIdx.x & 15;
  const int vt = blockIdx.x >> 4;
  const int l0 = lt * 64, v0 = vt * 64;
  const int tid = threadIdx.x;
  const int lv = tid & 63;
  #pragma unroll
  for (int k = 0; k < 16; ++k) {
    int ll = k * 4 + (tid >> 6);
    int v = v0 + lv;
    s[ll][lv] = (v < V) ? Wd[(size_t)(l0 + ll) * V + v] : 0.f;
  }
  __syncthreads();
  const int vv = tid >> 2, lq = tid & 3;
  bf16x8 o0, o1;
  #pragma unroll
  for (int j = 0; j < 8; ++j) {
    o0[j] = (bf16)s[lq * 16 + j][vv];
    o1[j] = (bf16)s[lq * 16 + 8 + j][vv];
  }
  bf16* dst = Wdt + (size_t)(v0 + vv) * 1024 + l0 + lq * 16;
  *(bf16x8*)dst = o0;
  *(bf16x8*)(dst + 8) = o1;
}

// ---------------- logits MFMA GEMM, coalesced LDS-staged epilogue ----------------
__global__ __launch_bounds__(256) void k_logits_mfma(
    const bf16* __restrict__ Ag, const bf16* __restrict__ Btg,
    const float* __restrict__ bd, float* __restrict__ out) {
  __shared__ __align__(16) char lds[65536];
  char* sA = lds;
  char* sB = lds + 16384;
  const int bid = blockIdx.x;
  const int wg = (bid & 7) * 188 + (bid >> 3);
  const int mt = wg / 94, nt = wg % 94;
  const int m0 = mt * 128, n0 = nt * 128;
  const int tid = threadIdx.x, w = tid >> 6, lane = tid & 63;
  const int wr = w >> 1, wc = w & 1;

  f32x4 acc[4][4];
  #pragma unroll
  for (int i = 0; i < 4; ++i)
    #pragma unroll
    for (int j = 0; j < 4; ++j) acc[i][j] = (f32x4){0.f, 0.f, 0.f, 0.f};

  int rowc[4], sloc[4];
  #pragma unroll
  for (int i = 0; i < 4; ++i) {
    int c = i * 4 + w;
    rowc[i] = c * 8 + (lane >> 3);
    sloc[i] = (lane & 7) ^ (rowc[i] & 7);
  }

  for (int kk = 0; kk < 16; ++kk) {
    if (kk) __syncthreads();
    const char* ga = (const char*)Ag + kk * 128;
    const char* gb = (const char*)Btg + kk * 128;
    #pragma unroll
    for (int i = 0; i < 4; ++i) {
      int c = i * 4 + w;
      load_lds16(ga + (size_t)(m0 + rowc[i]) * 2048 + sloc[i] * 16, sA + c * 1024);
      load_lds16(gb + (size_t)(n0 + rowc[i]) * 2048 + sloc[i] * 16, sB + c * 1024);
    }
    __syncthreads();
    #pragma unroll
    for (int ks = 0; ks < 2; ++ks) {
      bf16x8 av[4], bv[4];
      #pragma unroll
      for (int f = 0; f < 4; ++f) {
        int ra = wr * 64 + f * 16 + (lane & 15);
        int ca = (ks * 4 + (lane >> 4)) ^ (ra & 7);
        av[f] = *(const bf16x8*)(sA + ra * 128 + ca * 16);
        int rb = wc * 64 + f * 16 + (lane & 15);
        int cb = (ks * 4 + (lane >> 4)) ^ (rb & 7);
        bv[f] = *(const bf16x8*)(sB + rb * 128 + cb * 16);
      }
      #pragma unroll
      for (int fm = 0; fm < 4; ++fm)
        #pragma unroll
        for (int fn = 0; fn < 4; ++fn)
          acc[fm][fn] = __builtin_amdgcn_mfma_f32_16x16x32_bf16(
              av[fm], bv[fn], acc[fm][fn], 0, 0, 0);
    }
  }

  // epilogue: stage full 128x128 fp32 tile in LDS, then coalesced float4 rows
  __syncthreads();
  float* ctile = (float*)lds;
  const int c0o = n0 + wc * 64 + (lane & 15);
  #pragma unroll
  for (int fn = 0; fn < 4; ++fn) {
    int colg = c0o + fn * 16;
    float bv = (colg < V) ? bd[colg] : 0.f;
    int col = wc * 64 + fn * 16 + (lane & 15);
    #pragma unroll
    for (int fm = 0; fm < 4; ++fm) {
      int row = wr * 64 + fm * 16 + ((lane >> 4) << 2);
      #pragma unroll
      for (int r = 0; r < 4; ++r)
        ctile[(row + r) * 128 + col] = acc[fm][fn][r] + bv;
    }
  }
  __syncthreads();
  #pragma unroll
  for (int it = 0; it < 16; ++it) {
    int idx = it * 256 + tid;
    int row = idx >> 5, ch = idx & 31;
    int colg = n0 + ch * 4;
    if (colg < V)
      *(float4*)&out[(size_t)(m0 + row) * V + colg] = *(float4*)&ctile[row * 128 + ch * 4];
  }
}

// ---------------- row softmax (fp32 in place) ----------------
__global__ __launch_bounds__(256) void k_softmax(float* __restrict__ logits) {
  __shared__ float srow[V];
  __shared__ float sred[4];
  float* row = logits + (size_t)blockIdx.x * V;
  const int tid = threadIdx.x;
  const float4* rv = (const float4*)row;
  float4* sv = (float4*)srow;
  float m = -3.4e38f;
  for (int i = tid; i < 3000; i += 256) {
    float4 x = rv[i];
    sv[i] = x;
    m = fmaxf(fmaxf(m, fmaxf(x.x, x.y)), fmaxf(x.z, x.w));
  }
  #pragma unroll
  for (int off = 32; off; off >>= 1) m = fmaxf(m, __shfl_xor(m, off));
  if ((tid & 63) == 0) sred[tid >> 6] = m;
  __syncthreads();
  const float M = fmaxf(fmaxf(sred[0], sred[1]), fmaxf(sred[2], sred[3]));
  float s = 0.f;
  for (int i = tid; i < 3000; i += 256) {
    float4 x = sv[i];
    x.x = __expf(x.x - M); x.y = __expf(x.y - M);
    x.z = __expf(x.z - M); x.w = __expf(x.w - M);
    sv[i] = x;
    s += x.x + x.y + x.z + x.w;
  }
  #pragma unroll
  for (int off = 32; off; off >>= 1) s += __shfl_xor(s, off);
  __syncthreads();
  if ((tid & 63) == 0) sred[tid >> 6] = s;
  __syncthreads();
  const float inv = 1.f / (sred[0] + sred[1] + sred[2] + sred[3]);
  float4* ov = (float4*)row;
  for (int i = tid; i < 3000; i += 256) {
    float4 x = sv[i];
    x.x *= inv; x.y *= inv; x.z *= inv; x.w *= inv;
    ov[i] = x;
  }
}

__global__ void k_finalize(const float* __restrict__ hf32, const float* __restrict__ cst,
                           float* __restrict__ oh, float* __restrict__ oc) {
  int i = blockIdx.x * 256 + threadIdx.x;
  if (i < B * L) {
    oh[i] = hf32[i];
    oc[i] = cst[i];
  }
}

// ---------------- launch ----------------

extern "C" void kernel_launch(void* const* d_in, const int* in_sizes, int n_in,
                              void* d_out, int out_size, void* d_ws, size_t ws_size,
                              hipStream_t stream) {
  const int*   targets = (const int*)d_in[0];
  const float* options = (const float*)d_in[1];
  const float* h0      = (const float*)d_in[2];
  const float* c0      = (const float*)d_in[3];
  const float* emb     = (const float*)d_in[4];
  const float* W2      = (const float*)d_in[7];
  const float* Va      = (const float*)d_in[9];
  const float* Wx      = (const float*)d_in[11];
  const float* Wh      = (const float*)d_in[12];
  const float* bl      = (const float*)d_in[13];
  const float* Wd      = (const float*)d_in[14];
  const float* bd      = (const float*)d_in[15];

  float* out      = (float*)d_out;
  float* out_h    = out + N_PROBS;
  float* out_c    = out_h + (size_t)B * L;
  float* out_attn = out_c + (size_t)B * L;

  // ---- workspace layout (bytes), total 41,037,824 B = 39.1 MiB ----
  char* wsb = (char*)d_ws;
  float* v2     = (float*)(wsb);
  float* wat    = (float*)(wsb + 4096);
  float* ctx    = (float*)(wsb + 12288);
  float* cx     = (float*)(wsb + 143360);
  float* cst    = (float*)(wsb + 667648);
  bf16*  hA_hi  = (bf16*)(wsb + 798720);
  bf16*  hA_lo  = (bf16*)(wsb + 864256);
  bf16*  hB_hi  = (bf16*)(wsb + 929792);
  bf16*  hB_lo  = (bf16*)(wsb + 995328);
  float* hf32   = (float*)(wsb + 1060864);
  bf16*  Eg_hi  = (bf16*)(wsb + 1191936);
  bf16*  Eg_lo  = (bf16*)(wsb + 2240512);
  bf16*  Wx2t_hi= (bf16*)(wsb + 3289088);
  bf16*  Wx2t_lo= (bf16*)(wsb + 5386240);
  bf16*  Hb16   = (bf16*)(wsb + 1191936);   // alias Eg/Wx2t after pre-GEMM
  bf16*  Whp_hi = (bf16*)(wsb + 7483392);
  bf16*  Whp_lo = (bf16*)(wsb + 15872000);
  fp16*  pre16  = (fp16*)(wsb + 24260608);  // 16 MB
  float* cxp    = (float*)(wsb + 24260608); // alias pre16 (pre-GEMM phase only)
  bf16*  Wdt    = (bf16*)(wsb + 7483392);   // alias Whp+pre16 (post-recurrence)

  // attention (h-independent)
  k_v2<<<256, 256, 0, stream>>>(W2, Va, v2);
  k_score<<<512, 256, 0, stream>>>(options, v2, wat);
  k_attnctx<<<32, 256, 0, stream>>>(options, wat, out_attn, ctx);
  k_cx_part<<<512, 256, 0, stream>>>(ctx, Wx, cxp);
  k_cx_reduce<<<512, 256, 0, stream>>>(cxp, bl, cx);

  // transforms
  k_eg<<<2048, 256, 0, stream>>>(targets, emb, Eg_hi, Eg_lo);
  k_wx2t<<<256, 256, 0, stream>>>(Wx, Wx2t_hi, Wx2t_lo);
  k_whp<<<1024, 256, 0, stream>>>(Wh, Whp_hi, Whp_lo);

  // pre = Eg @ Wx2 + cx
  k_pre_mfma<<<512, 256, 0, stream>>>(Eg_hi, Eg_lo, Wx2t_hi, Wx2t_lo, cx, pre16);
  k_h0split<<<128, 256, 0, stream>>>(h0, hA_hi, hA_lo, hf32);

  // persistent cooperative recurrence (one launch for all 64 steps)
  {
    const bf16* a_whph = Whp_hi; const bf16* a_whpl = Whp_lo;
    const fp16* a_pre = pre16;
    bf16* a_hah = hA_hi; bf16* a_hal = hA_lo;
    bf16* a_hbh = hB_hi; bf16* a_hbl = hB_lo;
    const float* a_c0 = c0;
    float* a_cst = cst; float* a_hf32 = hf32;
    bf16* a_hb16 = Hb16;
    void* args[] = {&a_whph, &a_whpl, &a_pre, &a_hah, &a_hal, &a_hbh, &a_hbl,
                    &a_c0, &a_cst, &a_hf32, &a_hb16};
    hipLaunchCooperativeKernel((void*)k_rec, dim3(256), dim3(512), args, 0, stream);
  }

  // logits + softmax + finalize
  k_wdt<<<188 * 16, 256, 0, stream>>>(Wd, Wdt);
  k_logits_mfma<<<1504, 256, 0, stream>>>(Hb16, Wdt, bd, out);
  k_softmax<<<B * T, 256, 0, stream>>>(out);
  k_finalize<<<128, 256, 0, stream>>>(hf32, cst, out_h, out_c);
}

// Round 6
// 586.069 us; speedup vs baseline: 4.4509x; 4.4509x over previous
//
#include <hip/hip_runtime.h>
#include <math.h>

// Decoder_910533066914 — R6: per-step launches restored (graph launch = cheap
// grid sync; cg::grid.sync measured 37µs/step in R5), recurrence + logits in
// fp16 single-pass MFMA (1/3 the MFMA work, 1/2 the bytes of R4's hi/lo).

typedef __bf16 bf16;
typedef _Float16 fp16;
typedef __attribute__((ext_vector_type(8))) __bf16 bf16x8;
typedef __attribute__((ext_vector_type(8))) _Float16 fp16x8;
typedef __attribute__((ext_vector_type(4))) float f32x4;

constexpr int B = 32, T = 64, S = 64, D = 1024, A = 512, E = 256, L = 1024, V = 12000;
constexpr int G = 4096;
constexpr size_t N_PROBS = (size_t)B * T * V;

__device__ inline void load_lds16(const void* g, void* l) {
  __builtin_amdgcn_global_load_lds(
      (const __attribute__((address_space(1))) unsigned int*)g,
      (__attribute__((address_space(3))) unsigned int*)l, 16, 0, 0);
}

// ---------------- attention precompute ----------------

__global__ void k_v2(const float* __restrict__ W2, const float* __restrict__ Va,
                     float* __restrict__ v2) {
  int gw = (blockIdx.x * blockDim.x + threadIdx.x) >> 6;
  int lane = threadIdx.x & 63;
  if (gw >= D) return;
  float acc = 0.f;
  for (int a = lane; a < A; a += 64) acc += W2[(size_t)gw * A + a] * Va[a];
  #pragma unroll
  for (int off = 32; off; off >>= 1) acc += __shfl_down(acc, off);
  if (lane == 0) v2[gw] = acc;
}

__global__ void k_score(const float* __restrict__ options, const float* __restrict__ v2,
                        float* __restrict__ w) {
  int row = (blockIdx.x * blockDim.x + threadIdx.x) >> 6;
  int lane = threadIdx.x & 63;
  if (row >= B * S) return;
  const float* orow = options + (size_t)row * D;
  float acc = 0.f;
  for (int d = lane; d < D; d += 64) acc += orow[d] * v2[d];
  #pragma unroll
  for (int off = 32; off; off >>= 1) acc += __shfl_down(acc, off);
  if (lane == 0) w[row] = acc;
}

// fused: softmax over s + attention output + context (one block per b)
__global__ __launch_bounds__(256) void k_attnctx(
    const float* __restrict__ options, const float* __restrict__ wat,
    float* __restrict__ oattn, float* __restrict__ ctx) {
  __shared__ float sw[64];
  const int b = blockIdx.x, tid = threadIdx.x;
  if (tid < 64) {
    float v = wat[b * 64 + tid];
    float m = v;
    #pragma unroll
    for (int off = 32; off; off >>= 1) m = fmaxf(m, __shfl_xor(m, off));
    float e = expf(v - m);
    float s = e;
    #pragma unroll
    for (int off = 32; off; off >>= 1) s += __shfl_xor(s, off);
    float res = e / s;
    sw[tid] = res;
    oattn[b * 64 + tid] = res;
  }
  __syncthreads();
  for (int d = tid; d < D; d += 256) {
    float acc = 0.f;
    #pragma unroll 8
    for (int s = 0; s < 64; ++s)
      acc += sw[s] * options[((size_t)(b * 64 + s)) * D + d];
    ctx[b * D + d] = acc;
  }
}

// ---------------- cx = bl + ctx@Wx1, split-K ----------------
__global__ __launch_bounds__(256) void k_cx_part(
    const float* __restrict__ ctx, const float* __restrict__ Wx,
    float* __restrict__ cxp) {
  const int jt = blockIdx.x & 15;
  const int bg = (blockIdx.x >> 4) & 3;
  const int kc = blockIdx.x >> 6;
  const int j = jt * 256 + threadIdx.x;
  const int b0 = bg * 8, d0 = kc * 128;
  float acc[8];
  #pragma unroll
  for (int bb = 0; bb < 8; ++bb) acc[bb] = 0.f;
  for (int d = 0; d < 128; ++d) {
    float wv = Wx[(size_t)(d0 + d) * G + j];
    #pragma unroll
    for (int bb = 0; bb < 8; ++bb)
      acc[bb] = fmaf(ctx[(b0 + bb) * D + d0 + d], wv, acc[bb]);
  }
  #pragma unroll
  for (int bb = 0; bb < 8; ++bb)
    cxp[((size_t)kc * 32 + b0 + bb) * G + j] = acc[bb];
}

__global__ void k_cx_reduce(const float* __restrict__ cxp, const float* __restrict__ bl,
                            float* __restrict__ cx) {
  int i = blockIdx.x * 256 + threadIdx.x;
  float s = bl[i & 4095];
  #pragma unroll
  for (int kc = 0; kc < 8; ++kc) s += cxp[(size_t)kc * 131072 + i];
  cx[i] = s;
}

// ---------------- gathers / transposes ----------------

__global__ void k_eg(const int* __restrict__ targets, const float* __restrict__ emb,
                     bf16* __restrict__ eg_hi, bf16* __restrict__ eg_lo) {
  int r = blockIdx.x, e = threadIdx.x;
  int tok = targets[r];
  float x = emb[(size_t)tok * E + e];
  bf16 hi = (bf16)x;
  eg_hi[(size_t)r * E + e] = hi;
  eg_lo[(size_t)r * E + e] = (bf16)(x - (float)hi);
}

__global__ __launch_bounds__(256) void k_wx2t(const float* __restrict__ Wx,
                                              bf16* __restrict__ t_hi,
                                              bf16* __restrict__ t_lo) {
  __shared__ float s[64][65];
  const int et = blockIdx.x >> 6, jt = blockIdx.x & 63;
  const int e0 = et * 64, j0 = jt * 64;
  const int tid = threadIdx.x;
  const int jj = tid & 63;
  #pragma unroll
  for (int k = 0; k < 16; ++k) {
    int ee = k * 4 + (tid >> 6);
    s[ee][jj] = Wx[(size_t)(D + e0 + ee) * G + j0 + jj];
  }
  __syncthreads();
  const int jc = tid >> 2, eq = tid & 3;
  bf16x8 h0, h1, l0, l1;
  #pragma unroll
  for (int i = 0; i < 8; ++i) {
    float a = s[eq * 16 + i][jc], b = s[eq * 16 + 8 + i][jc];
    bf16 ah = (bf16)a, bh = (bf16)b;
    h0[i] = ah; l0[i] = (bf16)(a - (float)ah);
    h1[i] = bh; l1[i] = (bf16)(b - (float)bh);
  }
  size_t dst = (size_t)(j0 + jc) * E + e0 + eq * 16;
  *(bf16x8*)(t_hi + dst) = h0; *(bf16x8*)(t_hi + dst + 8) = h1;
  *(bf16x8*)(t_lo + dst) = l0; *(bf16x8*)(t_lo + dst + 8) = l1;
}

// Whp[rowp][l] = Wh[l][col] fp16, rowp = (jj>>2)*16 + g*4 + (jj&3), col = g*1024+jj
__global__ __launch_bounds__(256) void k_whp(const float* __restrict__ Wh,
                                             fp16* __restrict__ p) {
  __shared__ float s[64][65];
  const int lt = blockIdx.x & 15, ct = blockIdx.x >> 4;
  const int l0 = lt * 64, c0 = ct * 64;
  const int tid = threadIdx.x;
  const int cc = tid & 63;
  #pragma unroll
  for (int k = 0; k < 16; ++k) {
    int ll = k * 4 + (tid >> 6);
    s[ll][cc] = Wh[(size_t)(l0 + ll) * G + c0 + cc];
  }
  __syncthreads();
  const int c = tid >> 2, lq = tid & 3;
  const int col = c0 + c, g = col >> 10, jj = col & 1023;
  const int rowp = ((jj >> 2) << 4) + (g << 2) + (jj & 3);
  fp16x8 o0, o1;
  #pragma unroll
  for (int i = 0; i < 8; ++i) {
    o0[i] = (fp16)s[lq * 16 + i][c];
    o1[i] = (fp16)s[lq * 16 + 8 + i][c];
  }
  size_t dst = (size_t)rowp * L + l0 + lq * 16;
  *(fp16x8*)(p + dst) = o0;
  *(fp16x8*)(p + dst + 8) = o1;
}

__global__ void k_h0split(const float* __restrict__ h0, const float* __restrict__ c0,
                          fp16* __restrict__ h16, float* __restrict__ cst,
                          float* __restrict__ hf32) {
  int i = blockIdx.x * 256 + threadIdx.x;
  float x = h0[i];
  h16[i] = (fp16)x;
  hf32[i] = x;
  cst[i] = c0[i];
}

// ---------------- pre = Eg@Wx2t^T + cx -> fp16 [2048][4096] (bf16 hi/lo) ----
__global__ __launch_bounds__(256) void k_pre_mfma(
    const bf16* __restrict__ Ah, const bf16* __restrict__ Al,
    const bf16* __restrict__ Bh, const bf16* __restrict__ Bl,
    const float* __restrict__ cx, fp16* __restrict__ pre16) {
  __shared__ __align__(16) char lds[65536];
  char* sAh = lds;
  char* sAl = lds + 16384;
  char* sBh = lds + 32768;
  char* sBl = lds + 49152;
  const int bid = blockIdx.x;
  const int swz = (bid & 7) * 64 + (bid >> 3);
  const int mt = swz >> 5, nt = swz & 31;
  const int m0 = mt * 128, n0 = nt * 128;
  const int tid = threadIdx.x, w = tid >> 6, lane = tid & 63;
  const int wr = w >> 1, wc = w & 1;

  f32x4 acc[4][4];
  #pragma unroll
  for (int i = 0; i < 4; ++i)
    #pragma unroll
    for (int j = 0; j < 4; ++j) acc[i][j] = (f32x4){0.f, 0.f, 0.f, 0.f};

  int rowc[4], sloc[4];
  #pragma unroll
  for (int i = 0; i < 4; ++i) {
    int c = i * 4 + w;
    rowc[i] = c * 8 + (lane >> 3);
    sloc[i] = (lane & 7) ^ (rowc[i] & 7);
  }

  for (int kk = 0; kk < 4; ++kk) {
    if (kk) __syncthreads();
    const char* gah = (const char*)Ah + kk * 128;
    const char* gal = (const char*)Al + kk * 128;
    const char* gbh = (const char*)Bh + kk * 128;
    const char* gbl = (const char*)Bl + kk * 128;
    #pragma unroll
    for (int i = 0; i < 4; ++i) {
      int c = i * 4 + w;
      load_lds16(gah + (size_t)(m0 + rowc[i]) * 512 + sloc[i] * 16, sAh + c * 1024);
      load_lds16(gal + (size_t)(m0 + rowc[i]) * 512 + sloc[i] * 16, sAl + c * 1024);
      load_lds16(gbh + (size_t)(n0 + rowc[i]) * 512 + sloc[i] * 16, sBh + c * 1024);
      load_lds16(gbl + (size_t)(n0 + rowc[i]) * 512 + sloc[i] * 16, sBl + c * 1024);
    }
    __syncthreads();
    #pragma unroll
    for (int ks = 0; ks < 2; ++ks) {
      bf16x8 avh[4], avl[4], bvh[4], bvl[4];
      #pragma unroll
      for (int f = 0; f < 4; ++f) {
        int ra = wr * 64 + f * 16 + (lane & 15);
        int ca = (ks * 4 + (lane >> 4)) ^ (ra & 7);
        avh[f] = *(const bf16x8*)(sAh + ra * 128 + ca * 16);
        avl[f] = *(const bf16x8*)(sAl + ra * 128 + ca * 16);
        int rb = wc * 64 + f * 16 + (lane & 15);
        int cb = (ks * 4 + (lane >> 4)) ^ (rb & 7);
        bvh[f] = *(const bf16x8*)(sBh + rb * 128 + cb * 16);
        bvl[f] = *(const bf16x8*)(sBl + rb * 128 + cb * 16);
      }
      #pragma unroll
      for (int fm = 0; fm < 4; ++fm)
        #pragma unroll
        for (int fn = 0; fn < 4; ++fn) {
          acc[fm][fn] = __builtin_amdgcn_mfma_f32_16x16x32_bf16(avh[fm], bvh[fn], acc[fm][fn], 0, 0, 0);
          acc[fm][fn] = __builtin_amdgcn_mfma_f32_16x16x32_bf16(avh[fm], bvl[fn], acc[fm][fn], 0, 0, 0);
          acc[fm][fn] = __builtin_amdgcn_mfma_f32_16x16x32_bf16(avl[fm], bvh[fn], acc[fm][fn], 0, 0, 0);
        }
    }
  }

  const int r0o = m0 + wr * 64 + ((lane >> 4) << 2);
  const int c0o = n0 + wc * 64 + (lane & 15);
  #pragma unroll
  for (int fn = 0; fn < 4; ++fn) {
    int colg = c0o + fn * 16;
    #pragma unroll
    for (int fm = 0; fm < 4; ++fm) {
      #pragma unroll
      for (int r = 0; r < 4; ++r) {
        int row = r0o + fm * 16 + r;
        float v = acc[fm][fn][r] + cx[(size_t)(row >> 6) * G + colg];
        pre16[(size_t)row * G + colg] = (fp16)v;
      }
    }
  }
}

// ---------------- recurrence step (fp16 MFMA, 256 blocks x 512 thr) ----------
// Block jb owns units j = jb*4..+3 (16 Whp rows). Wave w: k-slice w*128..+128.
__global__ __launch_bounds__(512) void k_step4(
    const fp16* __restrict__ Whp, const fp16* __restrict__ pre16,
    const fp16* __restrict__ hin, fp16* __restrict__ hout,
    float* __restrict__ cst, float* __restrict__ hf32,
    fp16* __restrict__ Hb16, int t) {
  __shared__ float zred[8 * 2 * 64 * 4]; // 16 KB
  __shared__ float zf[32][16];           // 2 KB
  const int jb = blockIdx.x;
  const int tid = threadIdx.x;
  const int w = tid >> 6, lane = tid & 63;
  const int fr = lane & 15, kc = lane >> 4;

  // gate-phase prefetch (overlaps MFMA)
  float pf[4];
  float cprev = 0.f;
  const int gb = tid >> 2, gjo = tid & 3, gj = jb * 4 + gjo;
  if (tid < 128) {
    const size_t pbase = (size_t)(gb * 64 + t) * G + gj;
    #pragma unroll
    for (int g = 0; g < 4; ++g) pf[g] = (float)pre16[pbase + g * 1024];
    cprev = cst[gb * 1024 + gj];
  }

  f32x4 acc[2];
  acc[0] = (f32x4){0.f, 0.f, 0.f, 0.f};
  acc[1] = (f32x4){0.f, 0.f, 0.f, 0.f};
  const fp16* bb = Whp + (size_t)(jb * 16 + fr) * L;
  #pragma unroll
  for (int kk = 0; kk < 4; ++kk) {
    const int k0 = (w * 4 + kk) * 32 + kc * 8;
    fp16x8 bv = *(const fp16x8*)(bb + k0);
    #pragma unroll
    for (int m = 0; m < 2; ++m) {
      fp16x8 av = *(const fp16x8*)(hin + (size_t)(m * 16 + fr) * L + k0);
      acc[m] = __builtin_amdgcn_mfma_f32_16x16x32_f16(av, bv, acc[m], 0, 0, 0);
    }
  }
  #pragma unroll
  for (int m = 0; m < 2; ++m)
    *(f32x4*)&zred[((w * 2 + m) * 64 + lane) * 4] = acc[m];
  __syncthreads();
  {
    const int b = tid >> 4, c = tid & 15;
    const int lane2 = (((b & 15) >> 2) << 4) | c;
    const int reg = b & 3, m = b >> 4;
    float s = 0.f;
    #pragma unroll
    for (int ww = 0; ww < 8; ++ww)
      s += zred[((ww * 2 + m) * 64 + lane2) * 4 + reg];
    zf[b][c] = s;
  }
  __syncthreads();
  if (tid < 128) {
    float zi = zf[gb][gjo] + pf[0];
    float zff = zf[gb][4 + gjo] + pf[1];
    float zg = zf[gb][8 + gjo] + pf[2];
    float zo = zf[gb][12 + gjo] + pf[3];
    float si = 1.f / (1.f + expf(-zi));
    float sf = 1.f / (1.f + expf(-zff));
    float tg = tanhf(zg);
    float so = 1.f / (1.f + expf(-zo));
    float cn = sf * cprev + si * tg;
    float hn = so * tanhf(cn);
    const int hi_idx = gb * 1024 + gj;
    cst[hi_idx] = cn;
    hout[hi_idx] = (fp16)hn;
    hf32[hi_idx] = hn;
    Hb16[(size_t)(gb * 64 + t) * L + gj] = (fp16)hn;
  }
}

// ---------------- Wd -> Wdt fp16 ----------------
__global__ __launch_bounds__(256) void k_wdt(const float* __restrict__ Wd,
                                             fp16* __restrict__ Wdt) {
  __shared__ float s[64][65];
  const int lt = blockIdx.x & 15;
  const int vt = blockIdx.x >> 4;
  const int l0 = lt * 64, v0 = vt * 64;
  const int tid = threadIdx.x;
  const int lv = tid & 63;
  #pragma unroll
  for (int k = 0; k < 16; ++k) {
    int ll = k * 4 + (tid >> 6);
    int v = v0 + lv;
    s[ll][lv] = (v < V) ? Wd[(size_t)(l0 + ll) * V + v] : 0.f;
  }
  __syncthreads();
  const int vv = tid >> 2, lq = tid & 3;
  fp16x8 o0, o1;
  #pragma unroll
  for (int j = 0; j < 8; ++j) {
    o0[j] = (fp16)s[lq * 16 + j][vv];
    o1[j] = (fp16)s[lq * 16 + 8 + j][vv];
  }
  fp16* dst = Wdt + (size_t)(v0 + vv) * 1024 + l0 + lq * 16;
  *(fp16x8*)dst = o0;
  *(fp16x8*)(dst + 8) = o1;
}

// ---------------- logits fp16 MFMA GEMM, coalesced LDS-staged epilogue -------
__global__ __launch_bounds__(256) void k_logits_mfma(
    const fp16* __restrict__ Ag, const fp16* __restrict__ Btg,
    const float* __restrict__ bd, float* __restrict__ out) {
  __shared__ __align__(16) char lds[65536];
  char* sA = lds;
  char* sB = lds + 16384;
  const int bid = blockIdx.x;
  const int wg = (bid & 7) * 188 + (bid >> 3);
  const int mt = wg / 94, nt = wg % 94;
  const int m0 = mt * 128, n0 = nt * 128;
  const int tid = threadIdx.x, w = tid >> 6, lane = tid & 63;
  const int wr = w >> 1, wc = w & 1;

  f32x4 acc[4][4];
  #pragma unroll
  for (int i = 0; i < 4; ++i)
    #pragma unroll
    for (int j = 0; j < 4; ++j) acc[i][j] = (f32x4){0.f, 0.f, 0.f, 0.f};

  int rowc[4], sloc[4];
  #pragma unroll
  for (int i = 0; i < 4; ++i) {
    int c = i * 4 + w;
    rowc[i] = c * 8 + (lane >> 3);
    sloc[i] = (lane & 7) ^ (rowc[i] & 7);
  }

  for (int kk = 0; kk < 16; ++kk) {
    if (kk) __syncthreads();
    const char* ga = (const char*)Ag + kk * 128;
    const char* gb = (const char*)Btg + kk * 128;
    #pragma unroll
    for (int i = 0; i < 4; ++i) {
      int c = i * 4 + w;
      load_lds16(ga + (size_t)(m0 + rowc[i]) * 2048 + sloc[i] * 16, sA + c * 1024);
      load_lds16(gb + (size_t)(n0 + rowc[i]) * 2048 + sloc[i] * 16, sB + c * 1024);
    }
    __syncthreads();
    #pragma unroll
    for (int ks = 0; ks < 2; ++ks) {
      fp16x8 av[4], bv[4];
      #pragma unroll
      for (int f = 0; f < 4; ++f) {
        int ra = wr * 64 + f * 16 + (lane & 15);
        int ca = (ks * 4 + (lane >> 4)) ^ (ra & 7);
        av[f] = *(const fp16x8*)(sA + ra * 128 + ca * 16);
        int rb = wc * 64 + f * 16 + (lane & 15);
        int cb = (ks * 4 + (lane >> 4)) ^ (rb & 7);
        bv[f] = *(const fp16x8*)(sB + rb * 128 + cb * 16);
      }
      #pragma unroll
      for (int fm = 0; fm < 4; ++fm)
        #pragma unroll
        for (int fn = 0; fn < 4; ++fn)
          acc[fm][fn] = __builtin_amdgcn_mfma_f32_16x16x32_f16(
              av[fm], bv[fn], acc[fm][fn], 0, 0, 0);
    }
  }

  // epilogue: stage full 128x128 fp32 tile in LDS, then coalesced float4 rows
  __syncthreads();
  float* ctile = (float*)lds;
  const int c0o = n0 + wc * 64 + (lane & 15);
  #pragma unroll
  for (int fn = 0; fn < 4; ++fn) {
    int colg = c0o + fn * 16;
    float bv = (colg < V) ? bd[colg] : 0.f;
    int col = wc * 64 + fn * 16 + (lane & 15);
    #pragma unroll
    for (int fm = 0; fm < 4; ++fm) {
      int row = wr * 64 + fm * 16 + ((lane >> 4) << 2);
      #pragma unroll
      for (int r = 0; r < 4; ++r)
        ctile[(row + r) * 128 + col] = acc[fm][fn][r] + bv;
    }
  }
  __syncthreads();
  #pragma unroll
  for (int it = 0; it < 16; ++it) {
    int idx = it * 256 + tid;
    int row = idx >> 5, ch = idx & 31;
    int colg = n0 + ch * 4;
    if (colg < V)
      *(float4*)&out[(size_t)(m0 + row) * V + colg] = *(float4*)&ctile[row * 128 + ch * 4];
  }
}

// ---------------- row softmax ----------------
__global__ __launch_bounds__(256) void k_softmax(float* __restrict__ logits) {
  __shared__ float srow[V];
  __shared__ float sred[4];
  float* row = logits + (size_t)blockIdx.x * V;
  const int tid = threadIdx.x;
  const float4* rv = (const float4*)row;
  float4* sv = (float4*)srow;
  float m = -3.4e38f;
  for (int i = tid; i < 3000; i += 256) {
    float4 x = rv[i];
    sv[i] = x;
    m = fmaxf(fmaxf(m, fmaxf(x.x, x.y)), fmaxf(x.z, x.w));
  }
  #pragma unroll
  for (int off = 32; off; off >>= 1) m = fmaxf(m, __shfl_xor(m, off));
  if ((tid & 63) == 0) sred[tid >> 6] = m;
  __syncthreads();
  const float M = fmaxf(fmaxf(sred[0], sred[1]), fmaxf(sred[2], sred[3]));
  float s = 0.f;
  for (int i = tid; i < 3000; i += 256) {
    float4 x = sv[i];
    x.x = __expf(x.x - M); x.y = __expf(x.y - M);
    x.z = __expf(x.z - M); x.w = __expf(x.w - M);
    sv[i] = x;
    s += x.x + x.y + x.z + x.w;
  }
  #pragma unroll
  for (int off = 32; off; off >>= 1) s += __shfl_xor(s, off);
  __syncthreads();
  if ((tid & 63) == 0) sred[tid >> 6] = s;
  __syncthreads();
  const float inv = 1.f / (sred[0] + sred[1] + sred[2] + sred[3]);
  float4* ov = (float4*)row;
  for (int i = tid; i < 3000; i += 256) {
    float4 x = sv[i];
    x.x *= inv; x.y *= inv; x.z *= inv; x.w *= inv;
    ov[i] = x;
  }
}

__global__ void k_finalize(const float* __restrict__ hf32, const float* __restrict__ cst,
                           float* __restrict__ oh, float* __restrict__ oc) {
  int i = blockIdx.x * 256 + threadIdx.x;
  if (i < B * L) {
    oh[i] = hf32[i];
    oc[i] = cst[i];
  }
}

// ---------------- launch ----------------

extern "C" void kernel_launch(void* const* d_in, const int* in_sizes, int n_in,
                              void* d_out, int out_size, void* d_ws, size_t ws_size,
                              hipStream_t stream) {
  const int*   targets = (const int*)d_in[0];
  const float* options = (const float*)d_in[1];
  const float* h0      = (const float*)d_in[2];
  const float* c0      = (const float*)d_in[3];
  const float* emb     = (const float*)d_in[4];
  const float* W2      = (const float*)d_in[7];
  const float* Va      = (const float*)d_in[9];
  const float* Wx      = (const float*)d_in[11];
  const float* Wh      = (const float*)d_in[12];
  const float* bl      = (const float*)d_in[13];
  const float* Wd      = (const float*)d_in[14];
  const float* bd      = (const float*)d_in[15];

  float* out      = (float*)d_out;
  float* out_h    = out + N_PROBS;
  float* out_c    = out_h + (size_t)B * L;
  float* out_attn = out_c + (size_t)B * L;

  // ---- workspace layout (bytes), total ~31.1 MiB ----
  char* wsb = (char*)d_ws;
  float* v2     = (float*)(wsb);               // 4 KB
  float* wat    = (float*)(wsb + 4096);        // 8 KB
  float* ctx    = (float*)(wsb + 12288);       // 128 KB
  float* cx     = (float*)(wsb + 143360);      // 512 KB
  float* cst    = (float*)(wsb + 667648);      // 128 KB
  fp16*  hA     = (fp16*)(wsb + 798720);       // 64 KB
  fp16*  hB     = (fp16*)(wsb + 864256);       // 64 KB
  float* hf32   = (float*)(wsb + 929792);      // 128 KB -> 1060864
  // X region: Eg/Wx2t during precompute; Hb16 (fp16 4 MB) aliases after pre-GEMM
  bf16*  Eg_hi  = (bf16*)(wsb + 1191936);      // 1 MB
  bf16*  Eg_lo  = (bf16*)(wsb + 2240512);      // 1 MB
  bf16*  Wx2t_hi= (bf16*)(wsb + 3289088);      // 2 MB
  bf16*  Wx2t_lo= (bf16*)(wsb + 5386240);      // 2 MB -> 7483392
  fp16*  Hb16   = (fp16*)(wsb + 1191936);      // alias X base, 4 MB
  fp16*  Whp    = (fp16*)(wsb + 7483392);      // 4096*1024*2 = 8 MB -> 15872000
  fp16*  pre16  = (fp16*)(wsb + 15872000);     // 16 MB -> 32649216
  float* cxp    = (float*)(wsb + 15872000);    // alias pre16 (pre-GEMM phase only)
  fp16*  Wdt    = (fp16*)(wsb + 7483392);      // alias Whp+pre16 (post-recurrence, 24.6 MB)

  // attention (h-independent)
  k_v2<<<256, 256, 0, stream>>>(W2, Va, v2);
  k_score<<<512, 256, 0, stream>>>(options, v2, wat);
  k_attnctx<<<32, 256, 0, stream>>>(options, wat, out_attn, ctx);
  k_cx_part<<<512, 256, 0, stream>>>(ctx, Wx, cxp);
  k_cx_reduce<<<512, 256, 0, stream>>>(cxp, bl, cx);

  // transforms
  k_eg<<<2048, 256, 0, stream>>>(targets, emb, Eg_hi, Eg_lo);
  k_wx2t<<<256, 256, 0, stream>>>(Wx, Wx2t_hi, Wx2t_lo);
  k_whp<<<1024, 256, 0, stream>>>(Wh, Whp);

  // pre = Eg @ Wx2 + cx
  k_pre_mfma<<<512, 256, 0, stream>>>(Eg_hi, Eg_lo, Wx2t_hi, Wx2t_lo, cx, pre16);
  k_h0split<<<128, 256, 0, stream>>>(h0, c0, hA, cst, hf32);

  // recurrence: per-step launches (launch boundary = cheap grid sync)
  for (int t = 0; t < T; ++t) {
    const fp16* hin = (t & 1) ? hB : hA;
    fp16* hout = (t & 1) ? hA : hB;
    k_step4<<<256, 512, 0, stream>>>(Whp, pre16, hin, hout, cst, hf32, Hb16, t);
  }

  // logits + softmax + finalize
  k_wdt<<<188 * 16, 256, 0, stream>>>(Wd, Wdt);
  k_logits_mfma<<<1504, 256, 0, stream>>>(Hb16, Wdt, bd, out);
  k_softmax<<<B * T, 256, 0, stream>>>(out);
  k_finalize<<<128, 256, 0, stream>>>(hf32, cst, out_h, out_c);
}

// Round 7
// 560.356 us; speedup vs baseline: 4.6551x; 1.0459x over previous
//
#include <hip/hip_runtime.h>
#include <math.h>

// Decoder_910533066914 — R7: (1) column-major XCD swizzle in logits GEMM
// (R6's row-major chunking re-fetched all of Wdt per XCD: 8x24=192MB FETCH);
// (2) fp16 single-pass pre-GEMM; (3) prep permuted [t][jb][b][jo][g] so each
// recurrence block reads one contiguous 1KB chunk.

typedef __bf16 bf16;
typedef _Float16 fp16;
typedef __attribute__((ext_vector_type(8))) __bf16 bf16x8;
typedef __attribute__((ext_vector_type(8))) _Float16 fp16x8;
typedef __attribute__((ext_vector_type(4))) _Float16 fp16x4;
typedef __attribute__((ext_vector_type(4))) float f32x4;

constexpr int B = 32, T = 64, S = 64, D = 1024, A = 512, E = 256, L = 1024, V = 12000;
constexpr int G = 4096;
constexpr size_t N_PROBS = (size_t)B * T * V;

__device__ inline void load_lds16(const void* g, void* l) {
  __builtin_amdgcn_global_load_lds(
      (const __attribute__((address_space(1))) unsigned int*)g,
      (__attribute__((address_space(3))) unsigned int*)l, 16, 0, 0);
}

// ---------------- attention precompute ----------------

__global__ void k_v2(const float* __restrict__ W2, const float* __restrict__ Va,
                     float* __restrict__ v2) {
  int gw = (blockIdx.x * blockDim.x + threadIdx.x) >> 6;
  int lane = threadIdx.x & 63;
  if (gw >= D) return;
  float acc = 0.f;
  for (int a = lane; a < A; a += 64) acc += W2[(size_t)gw * A + a] * Va[a];
  #pragma unroll
  for (int off = 32; off; off >>= 1) acc += __shfl_down(acc, off);
  if (lane == 0) v2[gw] = acc;
}

__global__ void k_score(const float* __restrict__ options, const float* __restrict__ v2,
                        float* __restrict__ w) {
  int row = (blockIdx.x * blockDim.x + threadIdx.x) >> 6;
  int lane = threadIdx.x & 63;
  if (row >= B * S) return;
  const float* orow = options + (size_t)row * D;
  float acc = 0.f;
  for (int d = lane; d < D; d += 64) acc += orow[d] * v2[d];
  #pragma unroll
  for (int off = 32; off; off >>= 1) acc += __shfl_down(acc, off);
  if (lane == 0) w[row] = acc;
}

__global__ __launch_bounds__(256) void k_attnctx(
    const float* __restrict__ options, const float* __restrict__ wat,
    float* __restrict__ oattn, float* __restrict__ ctx) {
  __shared__ float sw[64];
  const int b = blockIdx.x, tid = threadIdx.x;
  if (tid < 64) {
    float v = wat[b * 64 + tid];
    float m = v;
    #pragma unroll
    for (int off = 32; off; off >>= 1) m = fmaxf(m, __shfl_xor(m, off));
    float e = expf(v - m);
    float s = e;
    #pragma unroll
    for (int off = 32; off; off >>= 1) s += __shfl_xor(s, off);
    float res = e / s;
    sw[tid] = res;
    oattn[b * 64 + tid] = res;
  }
  __syncthreads();
  for (int d = tid; d < D; d += 256) {
    float acc = 0.f;
    #pragma unroll 8
    for (int s = 0; s < 64; ++s)
      acc += sw[s] * options[((size_t)(b * 64 + s)) * D + d];
    ctx[b * D + d] = acc;
  }
}

// ---------------- cx = bl + ctx@Wx1, split-K ----------------
__global__ __launch_bounds__(256) void k_cx_part(
    const float* __restrict__ ctx, const float* __restrict__ Wx,
    float* __restrict__ cxp) {
  const int jt = blockIdx.x & 15;
  const int bg = (blockIdx.x >> 4) & 3;
  const int kc = blockIdx.x >> 6;
  const int j = jt * 256 + threadIdx.x;
  const int b0 = bg * 8, d0 = kc * 128;
  float acc[8];
  #pragma unroll
  for (int bb = 0; bb < 8; ++bb) acc[bb] = 0.f;
  for (int d = 0; d < 128; ++d) {
    float wv = Wx[(size_t)(d0 + d) * G + j];
    #pragma unroll
    for (int bb = 0; bb < 8; ++bb)
      acc[bb] = fmaf(ctx[(b0 + bb) * D + d0 + d], wv, acc[bb]);
  }
  #pragma unroll
  for (int bb = 0; bb < 8; ++bb)
    cxp[((size_t)kc * 32 + b0 + bb) * G + j] = acc[bb];
}

__global__ void k_cx_reduce(const float* __restrict__ cxp, const float* __restrict__ bl,
                            float* __restrict__ cx) {
  int i = blockIdx.x * 256 + threadIdx.x;
  float s = bl[i & 4095];
  #pragma unroll
  for (int kc = 0; kc < 8; ++kc) s += cxp[(size_t)kc * 131072 + i];
  cx[i] = s;
}

// ---------------- gathers / transposes (fp16 single) ----------------

__global__ void k_eg(const int* __restrict__ targets, const float* __restrict__ emb,
                     fp16* __restrict__ eg) {
  int r = blockIdx.x, e = threadIdx.x;
  int tok = targets[r];
  eg[(size_t)r * E + e] = (fp16)emb[(size_t)tok * E + e];
}

__global__ __launch_bounds__(256) void k_wx2t(const float* __restrict__ Wx,
                                              fp16* __restrict__ t16) {
  __shared__ float s[64][65];
  const int et = blockIdx.x >> 6, jt = blockIdx.x & 63;
  const int e0 = et * 64, j0 = jt * 64;
  const int tid = threadIdx.x;
  const int jj = tid & 63;
  #pragma unroll
  for (int k = 0; k < 16; ++k) {
    int ee = k * 4 + (tid >> 6);
    s[ee][jj] = Wx[(size_t)(D + e0 + ee) * G + j0 + jj];
  }
  __syncthreads();
  const int jc = tid >> 2, eq = tid & 3;
  fp16x8 o0, o1;
  #pragma unroll
  for (int i = 0; i < 8; ++i) {
    o0[i] = (fp16)s[eq * 16 + i][jc];
    o1[i] = (fp16)s[eq * 16 + 8 + i][jc];
  }
  size_t dst = (size_t)(j0 + jc) * E + e0 + eq * 16;
  *(fp16x8*)(t16 + dst) = o0;
  *(fp16x8*)(t16 + dst + 8) = o1;
}

// Whp[rowp][l] = Wh[l][col] fp16, rowp = (jj>>2)*16 + g*4 + (jj&3), col = g*1024+jj
__global__ __launch_bounds__(256) void k_whp(const float* __restrict__ Wh,
                                             fp16* __restrict__ p) {
  __shared__ float s[64][65];
  const int lt = blockIdx.x & 15, ct = blockIdx.x >> 4;
  const int l0 = lt * 64, c0 = ct * 64;
  const int tid = threadIdx.x;
  const int cc = tid & 63;
  #pragma unroll
  for (int k = 0; k < 16; ++k) {
    int ll = k * 4 + (tid >> 6);
    s[ll][cc] = Wh[(size_t)(l0 + ll) * G + c0 + cc];
  }
  __syncthreads();
  const int c = tid >> 2, lq = tid & 3;
  const int col = c0 + c, g = col >> 10, jj = col & 1023;
  const int rowp = ((jj >> 2) << 4) + (g << 2) + (jj & 3);
  fp16x8 o0, o1;
  #pragma unroll
  for (int i = 0; i < 8; ++i) {
    o0[i] = (fp16)s[lq * 16 + i][c];
    o1[i] = (fp16)s[lq * 16 + 8 + i][c];
  }
  size_t dst = (size_t)rowp * L + l0 + lq * 16;
  *(fp16x8*)(p + dst) = o0;
  *(fp16x8*)(p + dst + 8) = o1;
}

__global__ void k_h0split(const float* __restrict__ h0, const float* __restrict__ c0,
                          fp16* __restrict__ h16, float* __restrict__ cst,
                          float* __restrict__ hf32) {
  int i = blockIdx.x * 256 + threadIdx.x;
  float x = h0[i];
  h16[i] = (fp16)x;
  hf32[i] = x;
  cst[i] = c0[i];
}

// ---------------- pre = Eg@Wx2t^T + cx -> prep[t][jb][b][jo][g] fp16 ----------
__global__ __launch_bounds__(256) void k_pre_mfma(
    const fp16* __restrict__ Ag, const fp16* __restrict__ Bg,
    const float* __restrict__ cx, fp16* __restrict__ prep) {
  __shared__ __align__(16) char lds[32768];
  char* sA = lds;
  char* sB = lds + 16384;
  const int bid = blockIdx.x;
  const int swz = (bid & 7) * 64 + (bid >> 3);
  const int mt = swz >> 5, nt = swz & 31;
  const int m0 = mt * 128, n0 = nt * 128;
  const int tid = threadIdx.x, w = tid >> 6, lane = tid & 63;
  const int wr = w >> 1, wc = w & 1;

  f32x4 acc[4][4];
  #pragma unroll
  for (int i = 0; i < 4; ++i)
    #pragma unroll
    for (int j = 0; j < 4; ++j) acc[i][j] = (f32x4){0.f, 0.f, 0.f, 0.f};

  int rowc[4], sloc[4];
  #pragma unroll
  for (int i = 0; i < 4; ++i) {
    int c = i * 4 + w;
    rowc[i] = c * 8 + (lane >> 3);
    sloc[i] = (lane & 7) ^ (rowc[i] & 7);
  }

  for (int kk = 0; kk < 4; ++kk) {
    if (kk) __syncthreads();
    const char* ga = (const char*)Ag + kk * 128;
    const char* gb = (const char*)Bg + kk * 128;
    #pragma unroll
    for (int i = 0; i < 4; ++i) {
      int c = i * 4 + w;
      load_lds16(ga + (size_t)(m0 + rowc[i]) * 512 + sloc[i] * 16, sA + c * 1024);
      load_lds16(gb + (size_t)(n0 + rowc[i]) * 512 + sloc[i] * 16, sB + c * 1024);
    }
    __syncthreads();
    #pragma unroll
    for (int ks = 0; ks < 2; ++ks) {
      fp16x8 av[4], bv[4];
      #pragma unroll
      for (int f = 0; f < 4; ++f) {
        int ra = wr * 64 + f * 16 + (lane & 15);
        int ca = (ks * 4 + (lane >> 4)) ^ (ra & 7);
        av[f] = *(const fp16x8*)(sA + ra * 128 + ca * 16);
        int rb = wc * 64 + f * 16 + (lane & 15);
        int cb = (ks * 4 + (lane >> 4)) ^ (rb & 7);
        bv[f] = *(const fp16x8*)(sB + rb * 128 + cb * 16);
      }
      #pragma unroll
      for (int fm = 0; fm < 4; ++fm)
        #pragma unroll
        for (int fn = 0; fn < 4; ++fn)
          acc[fm][fn] = __builtin_amdgcn_mfma_f32_16x16x32_f16(
              av[fm], bv[fn], acc[fm][fn], 0, 0, 0);
    }
  }

  // epilogue: prep[((t*256 + jb)*32 + b)*16 + jo*4 + g]
  const int r0o = m0 + wr * 64 + ((lane >> 4) << 2);
  const int c0o = n0 + wc * 64 + (lane & 15);
  #pragma unroll
  for (int fn = 0; fn < 4; ++fn) {
    int colg = c0o + fn * 16;
    int g = colg >> 10, jj = colg & 1023;
    int jb = jj >> 2, jo = jj & 3;
    #pragma unroll
    for (int fm = 0; fm < 4; ++fm) {
      #pragma unroll
      for (int r = 0; r < 4; ++r) {
        int row = r0o + fm * 16 + r;
        int b = row >> 6, t = row & 63;
        float v = acc[fm][fn][r] + cx[(size_t)b * G + colg];
        prep[(((size_t)t * 256 + jb) * 32 + b) * 16 + jo * 4 + g] = (fp16)v;
      }
    }
  }
}

// ---------------- recurrence step (fp16 MFMA, 256 blocks x 512 thr) ----------
__global__ __launch_bounds__(512) void k_step4(
    const fp16* __restrict__ Whp, const fp16* __restrict__ prep,
    const fp16* __restrict__ hin, fp16* __restrict__ hout,
    float* __restrict__ cst, float* __restrict__ hf32,
    fp16* __restrict__ Hb16, int t) {
  __shared__ float zred[8 * 2 * 64 * 4]; // 16 KB
  __shared__ float zf[32][16];           // 2 KB
  const int jb = blockIdx.x;
  const int tid = threadIdx.x;
  const int w = tid >> 6, lane = tid & 63;
  const int fr = lane & 15, kc = lane >> 4;

  // gate-phase prefetch: one contiguous fp16x4 per thread (1 KB per block)
  float pf[4];
  float cprev = 0.f;
  const int gb = tid >> 2, gjo = tid & 3, gj = jb * 4 + gjo;
  if (tid < 128) {
    fp16x4 pv = *(const fp16x4*)(prep + (((size_t)t * 256 + jb) * 32 + gb) * 16 + gjo * 4);
    #pragma unroll
    for (int g = 0; g < 4; ++g) pf[g] = (float)pv[g];
    cprev = cst[gb * 1024 + gj];
  }

  f32x4 acc[2];
  acc[0] = (f32x4){0.f, 0.f, 0.f, 0.f};
  acc[1] = (f32x4){0.f, 0.f, 0.f, 0.f};
  const fp16* bb = Whp + (size_t)(jb * 16 + fr) * L;
  #pragma unroll
  for (int kk = 0; kk < 4; ++kk) {
    const int k0 = (w * 4 + kk) * 32 + kc * 8;
    fp16x8 bv = *(const fp16x8*)(bb + k0);
    #pragma unroll
    for (int m = 0; m < 2; ++m) {
      fp16x8 av = *(const fp16x8*)(hin + (size_t)(m * 16 + fr) * L + k0);
      acc[m] = __builtin_amdgcn_mfma_f32_16x16x32_f16(av, bv, acc[m], 0, 0, 0);
    }
  }
  #pragma unroll
  for (int m = 0; m < 2; ++m)
    *(f32x4*)&zred[((w * 2 + m) * 64 + lane) * 4] = acc[m];
  __syncthreads();
  {
    const int b = tid >> 4, c = tid & 15;
    const int lane2 = (((b & 15) >> 2) << 4) | c;
    const int reg = b & 3, m = b >> 4;
    float s = 0.f;
    #pragma unroll
    for (int ww = 0; ww < 8; ++ww)
      s += zred[((ww * 2 + m) * 64 + lane2) * 4 + reg];
    zf[b][c] = s;
  }
  __syncthreads();
  if (tid < 128) {
    float zi = zf[gb][gjo] + pf[0];
    float zff = zf[gb][4 + gjo] + pf[1];
    float zg = zf[gb][8 + gjo] + pf[2];
    float zo = zf[gb][12 + gjo] + pf[3];
    float si = 1.f / (1.f + expf(-zi));
    float sf = 1.f / (1.f + expf(-zff));
    float tg = tanhf(zg);
    float so = 1.f / (1.f + expf(-zo));
    float cn = sf * cprev + si * tg;
    float hn = so * tanhf(cn);
    const int hi_idx = gb * 1024 + gj;
    cst[hi_idx] = cn;
    hout[hi_idx] = (fp16)hn;
    hf32[hi_idx] = hn;
    Hb16[(size_t)(gb * 64 + t) * L + gj] = (fp16)hn;
  }
}

// ---------------- Wd -> Wdt fp16 ----------------
__global__ __launch_bounds__(256) void k_wdt(const float* __restrict__ Wd,
                                             fp16* __restrict__ Wdt) {
  __shared__ float s[64][65];
  const int lt = blockIdx.x & 15;
  const int vt = blockIdx.x >> 4;
  const int l0 = lt * 64, v0 = vt * 64;
  const int tid = threadIdx.x;
  const int lv = tid & 63;
  #pragma unroll
  for (int k = 0; k < 16; ++k) {
    int ll = k * 4 + (tid >> 6);
    int v = v0 + lv;
    s[ll][lv] = (v < V) ? Wd[(size_t)(l0 + ll) * V + v] : 0.f;
  }
  __syncthreads();
  const int vv = tid >> 2, lq = tid & 3;
  fp16x8 o0, o1;
  #pragma unroll
  for (int j = 0; j < 8; ++j) {
    o0[j] = (fp16)s[lq * 16 + j][vv];
    o1[j] = (fp16)s[lq * 16 + 8 + j][vv];
  }
  fp16* dst = Wdt + (size_t)(v0 + vv) * 1024 + l0 + lq * 16;
  *(fp16x8*)dst = o0;
  *(fp16x8*)(dst + 8) = o1;
}

// ---------------- logits fp16 MFMA GEMM (column-major XCD swizzle) ----------
__global__ __launch_bounds__(256) void k_logits_mfma(
    const fp16* __restrict__ Ag, const fp16* __restrict__ Btg,
    const float* __restrict__ bd, float* __restrict__ out) {
  __shared__ __align__(16) char lds[65536];
  char* sA = lds;
  char* sB = lds + 16384;
  const int bid = blockIdx.x;
  const int wg = (bid & 7) * 188 + (bid >> 3);
  const int nt = wg >> 4, mt = wg & 15;   // column-major: XCD covers all M, ~12 N-panels
  const int m0 = mt * 128, n0 = nt * 128;
  const int tid = threadIdx.x, w = tid >> 6, lane = tid & 63;
  const int wr = w >> 1, wc = w & 1;

  f32x4 acc[4][4];
  #pragma unroll
  for (int i = 0; i < 4; ++i)
    #pragma unroll
    for (int j = 0; j < 4; ++j) acc[i][j] = (f32x4){0.f, 0.f, 0.f, 0.f};

  int rowc[4], sloc[4];
  #pragma unroll
  for (int i = 0; i < 4; ++i) {
    int c = i * 4 + w;
    rowc[i] = c * 8 + (lane >> 3);
    sloc[i] = (lane & 7) ^ (rowc[i] & 7);
  }

  for (int kk = 0; kk < 16; ++kk) {
    if (kk) __syncthreads();
    const char* ga = (const char*)Ag + kk * 128;
    const char* gb = (const char*)Btg + kk * 128;
    #pragma unroll
    for (int i = 0; i < 4; ++i) {
      int c = i * 4 + w;
      load_lds16(ga + (size_t)(m0 + rowc[i]) * 2048 + sloc[i] * 16, sA + c * 1024);
      load_lds16(gb + (size_t)(n0 + rowc[i]) * 2048 + sloc[i] * 16, sB + c * 1024);
    }
    __syncthreads();
    #pragma unroll
    for (int ks = 0; ks < 2; ++ks) {
      fp16x8 av[4], bv[4];
      #pragma unroll
      for (int f = 0; f < 4; ++f) {
        int ra = wr * 64 + f * 16 + (lane & 15);
        int ca = (ks * 4 + (lane >> 4)) ^ (ra & 7);
        av[f] = *(const fp16x8*)(sA + ra * 128 + ca * 16);
        int rb = wc * 64 + f * 16 + (lane & 15);
        int cb = (ks * 4 + (lane >> 4)) ^ (rb & 7);
        bv[f] = *(const fp16x8*)(sB + rb * 128 + cb * 16);
      }
      #pragma unroll
      for (int fm = 0; fm < 4; ++fm)
        #pragma unroll
        for (int fn = 0; fn < 4; ++fn)
          acc[fm][fn] = __builtin_amdgcn_mfma_f32_16x16x32_f16(
              av[fm], bv[fn], acc[fm][fn], 0, 0, 0);
    }
  }

  // epilogue: stage 128x128 fp32 tile in LDS, coalesced float4 rows
  __syncthreads();
  float* ctile = (float*)lds;
  const int c0o = n0 + wc * 64 + (lane & 15);
  #pragma unroll
  for (int fn = 0; fn < 4; ++fn) {
    int colg = c0o + fn * 16;
    float bv = (colg < V) ? bd[colg] : 0.f;
    int col = wc * 64 + fn * 16 + (lane & 15);
    #pragma unroll
    for (int fm = 0; fm < 4; ++fm) {
      int row = wr * 64 + fm * 16 + ((lane >> 4) << 2);
      #pragma unroll
      for (int r = 0; r < 4; ++r)
        ctile[(row + r) * 128 + col] = acc[fm][fn][r] + bv;
    }
  }
  __syncthreads();
  #pragma unroll
  for (int it = 0; it < 16; ++it) {
    int idx = it * 256 + tid;
    int row = idx >> 5, ch = idx & 31;
    int colg = n0 + ch * 4;
    if (colg < V)
      *(float4*)&out[(size_t)(m0 + row) * V + colg] = *(float4*)&ctile[row * 128 + ch * 4];
  }
}

// ---------------- row softmax ----------------
__global__ __launch_bounds__(256) void k_softmax(float* __restrict__ logits) {
  __shared__ float srow[V];
  __shared__ float sred[4];
  float* row = logits + (size_t)blockIdx.x * V;
  const int tid = threadIdx.x;
  const float4* rv = (const float4*)row;
  float4* sv = (float4*)srow;
  float m = -3.4e38f;
  for (int i = tid; i < 3000; i += 256) {
    float4 x = rv[i];
    sv[i] = x;
    m = fmaxf(fmaxf(m, fmaxf(x.x, x.y)), fmaxf(x.z, x.w));
  }
  #pragma unroll
  for (int off = 32; off; off >>= 1) m = fmaxf(m, __shfl_xor(m, off));
  if ((tid & 63) == 0) sred[tid >> 6] = m;
  __syncthreads();
  const float M = fmaxf(fmaxf(sred[0], sred[1]), fmaxf(sred[2], sred[3]));
  float s = 0.f;
  for (int i = tid; i < 3000; i += 256) {
    float4 x = sv[i];
    x.x = __expf(x.x - M); x.y = __expf(x.y - M);
    x.z = __expf(x.z - M); x.w = __expf(x.w - M);
    sv[i] = x;
    s += x.x + x.y + x.z + x.w;
  }
  #pragma unroll
  for (int off = 32; off; off >>= 1) s += __shfl_xor(s, off);
  __syncthreads();
  if ((tid & 63) == 0) sred[tid >> 6] = s;
  __syncthreads();
  const float inv = 1.f / (sred[0] + sred[1] + sred[2] + sred[3]);
  float4* ov = (float4*)row;
  for (int i = tid; i < 3000; i += 256) {
    float4 x = sv[i];
    x.x *= inv; x.y *= inv; x.z *= inv; x.w *= inv;
    ov[i] = x;
  }
}

__global__ void k_finalize(const float* __restrict__ hf32, const float* __restrict__ cst,
                           float* __restrict__ oh, float* __restrict__ oc) {
  int i = blockIdx.x * 256 + threadIdx.x;
  if (i < B * L) {
    oh[i] = hf32[i];
    oc[i] = cst[i];
  }
}

// ---------------- launch ----------------

extern "C" void kernel_launch(void* const* d_in, const int* in_sizes, int n_in,
                              void* d_out, int out_size, void* d_ws, size_t ws_size,
                              hipStream_t stream) {
  const int*   targets = (const int*)d_in[0];
  const float* options = (const float*)d_in[1];
  const float* h0      = (const float*)d_in[2];
  const float* c0      = (const float*)d_in[3];
  const float* emb     = (const float*)d_in[4];
  const float* W2      = (const float*)d_in[7];
  const float* Va      = (const float*)d_in[9];
  const float* Wx      = (const float*)d_in[11];
  const float* Wh      = (const float*)d_in[12];
  const float* bl      = (const float*)d_in[13];
  const float* Wd      = (const float*)d_in[14];
  const float* bd      = (const float*)d_in[15];

  float* out      = (float*)d_out;
  float* out_h    = out + N_PROBS;
  float* out_c    = out_h + (size_t)B * L;
  float* out_attn = out_c + (size_t)B * L;

  // ---- workspace layout (bytes), total ~31.1 MiB ----
  char* wsb = (char*)d_ws;
  float* v2     = (float*)(wsb);               // 4 KB
  float* wat    = (float*)(wsb + 4096);        // 8 KB
  float* ctx    = (float*)(wsb + 12288);       // 128 KB
  float* cx     = (float*)(wsb + 143360);      // 512 KB
  float* cst    = (float*)(wsb + 667648);      // 128 KB
  fp16*  hA     = (fp16*)(wsb + 798720);       // 64 KB
  fp16*  hB     = (fp16*)(wsb + 864256);       // 64 KB
  float* hf32   = (float*)(wsb + 929792);      // 128 KB -> 1060864
  // X region: Eg/Wx2t during precompute; Hb16 (fp16 4 MB) aliases after pre-GEMM
  fp16*  Eg16   = (fp16*)(wsb + 1191936);      // 1 MB
  fp16*  Wx2t16 = (fp16*)(wsb + 2240512);      // 2 MB -> 4337664
  fp16*  Hb16   = (fp16*)(wsb + 1191936);      // alias X base, 4 MB
  fp16*  Whp    = (fp16*)(wsb + 7483392);      // 8 MB -> 15872000
  fp16*  prep   = (fp16*)(wsb + 15872000);     // 16 MB -> 32649216
  float* cxp    = (float*)(wsb + 15872000);    // alias prep (pre-GEMM phase only)
  fp16*  Wdt    = (fp16*)(wsb + 7483392);      // alias Whp+prep (post-recurrence)

  // attention (h-independent)
  k_v2<<<256, 256, 0, stream>>>(W2, Va, v2);
  k_score<<<512, 256, 0, stream>>>(options, v2, wat);
  k_attnctx<<<32, 256, 0, stream>>>(options, wat, out_attn, ctx);
  k_cx_part<<<512, 256, 0, stream>>>(ctx, Wx, cxp);
  k_cx_reduce<<<512, 256, 0, stream>>>(cxp, bl, cx);

  // transforms
  k_eg<<<2048, 256, 0, stream>>>(targets, emb, Eg16);
  k_wx2t<<<256, 256, 0, stream>>>(Wx, Wx2t16);
  k_whp<<<1024, 256, 0, stream>>>(Wh, Whp);

  // pre = Eg @ Wx2 + cx  (permuted prep layout)
  k_pre_mfma<<<512, 256, 0, stream>>>(Eg16, Wx2t16, cx, prep);
  k_h0split<<<128, 256, 0, stream>>>(h0, c0, hA, cst, hf32);

  // recurrence: per-step launches
  for (int t = 0; t < T; ++t) {
    const fp16* hin = (t & 1) ? hB : hA;
    fp16* hout = (t & 1) ? hA : hB;
    k_step4<<<256, 512, 0, stream>>>(Whp, prep, hin, hout, cst, hf32, Hb16, t);
  }

  // logits + softmax + finalize
  k_wdt<<<188 * 16, 256, 0, stream>>>(Wd, Wdt);
  k_logits_mfma<<<1504, 256, 0, stream>>>(Hb16, Wdt, bd, out);
  k_softmax<<<B * T, 256, 0, stream>>>(out);
  k_finalize<<<128, 256, 0, stream>>>(hf32, cst, out_h, out_c);
}